// Round 3
// baseline (145013.928 us; speedup 1.0000x reference)
//
#include <hip/hip_runtime.h>
#include <math.h>

#define T_SEQ 2048
#define BATCH 16
#define CH_T  256              // timesteps per chunk
#define CH_M  (CH_T*BATCH)     // 4096 rows per chunk
#define NCHUNK (T_SEQ/CH_T)    // 8
#define SCALE_K 0.125f         // 1/sqrt(H/NH) = 1/sqrt(64)

// ---------------------------------------------------------------------------
// Common tiled f32 GEMM body:  C[128,128] tile = act( A-tile @ W-tile^T ).
// A rows from Ap (K-major), W rows from Wp (K-major), writes Cp (ldc row
// stride, pre-offset to the tile's top-left). 256 threads, 8x8 micro-tile.
// ---------------------------------------------------------------------------
template<bool SILU>
__device__ __forceinline__ void gemm_body(const float* __restrict__ Ap,
                                          const float* __restrict__ Wp,
                                          float* __restrict__ Cp,
                                          int K, int ldc)
{
  __shared__ float As[16][132];
  __shared__ float Ws[16][132];
  const int tid = threadIdx.x;
  const int tx = tid & 15, ty = tid >> 4;
  float acc[8][8] = {};
  for (int k0 = 0; k0 < K; k0 += 16) {
#pragma unroll
    for (int i = 0; i < 2; ++i) {
      int idx = tid + i * 256;           // 0..511
      int r = idx >> 2, kq = idx & 3;    // row 0..127, k-quad 0..3
      float4 av = *(const float4*)(Ap + (size_t)r * K + k0 + kq * 4);
      float4 wv = *(const float4*)(Wp + (size_t)r * K + k0 + kq * 4);
      As[kq*4+0][r] = av.x; As[kq*4+1][r] = av.y;
      As[kq*4+2][r] = av.z; As[kq*4+3][r] = av.w;
      Ws[kq*4+0][r] = wv.x; Ws[kq*4+1][r] = wv.y;
      Ws[kq*4+2][r] = wv.z; Ws[kq*4+3][r] = wv.w;
    }
    __syncthreads();
#pragma unroll
    for (int kk = 0; kk < 16; ++kk) {
      float a[8], b[8];
      *(float4*)&a[0] = *(const float4*)&As[kk][ty*8];
      *(float4*)&a[4] = *(const float4*)&As[kk][ty*8+4];
      *(float4*)&b[0] = *(const float4*)&Ws[kk][tx*8];
      *(float4*)&b[4] = *(const float4*)&Ws[kk][tx*8+4];
#pragma unroll
      for (int i = 0; i < 8; ++i)
#pragma unroll
        for (int j = 0; j < 8; ++j)
          acc[i][j] = fmaf(a[i], b[j], acc[i][j]);
    }
    __syncthreads();
  }
#pragma unroll
  for (int i = 0; i < 8; ++i) {
    float* Cr = Cp + (size_t)(ty*8 + i) * ldc + tx*8;
#pragma unroll
    for (int j0 = 0; j0 < 8; j0 += 4) {
      float4 v;
      v.x = acc[i][j0+0]; v.y = acc[i][j0+1];
      v.z = acc[i][j0+2]; v.w = acc[i][j0+3];
      if (SILU) {
        v.x = v.x / (1.f + expf(-v.x));
        v.y = v.y / (1.f + expf(-v.y));
        v.z = v.z / (1.f + expf(-v.z));
        v.w = v.w / (1.f + expf(-v.w));
      }
      *(float4*)(Cr + j0) = v;
    }
  }
}

template<bool SILU>
__global__ __launch_bounds__(256, 2) void gemm_nt(
    const float* __restrict__ A, const float* __restrict__ W,
    float* __restrict__ C, int K, int ldc)
{
  const int bn = blockIdx.x, bm = blockIdx.y;
  gemm_body<SILU>(A + (size_t)bm * 128 * K,
                  W + (size_t)bn * 128 * K,
                  C + (size_t)bm * 128 * ldc + bn * 128, K, ldc);
}

// Fused q|k|v|gates GEMM: A [M,1024] x {Wq,Wk,Wv [512,1024], Wg [1536,1024]}
// -> C [M,3072] with column layout [q|k|v|g].
__global__ __launch_bounds__(256, 2) void gemm_qkvg(
    const float* __restrict__ A,
    const float* __restrict__ Wq, const float* __restrict__ Wk,
    const float* __restrict__ Wv, const float* __restrict__ Wg,
    float* __restrict__ C)
{
  const int bn = blockIdx.x, bm = blockIdx.y;   // bn 0..23
  const float* W; int wrow, ccol;
  if (bn < 4)       { W = Wq; wrow = bn * 128;        ccol = bn * 128; }
  else if (bn < 8)  { W = Wk; wrow = (bn - 4) * 128;  ccol = 512  + (bn - 4) * 128; }
  else if (bn < 12) { W = Wv; wrow = (bn - 8) * 128;  ccol = 1024 + (bn - 8) * 128; }
  else              { W = Wg; wrow = (bn - 12) * 128; ccol = 1536 + (bn - 12) * 128; }
  gemm_body<false>(A + (size_t)bm * 128 * 1024,
                   W + (size_t)wrow * 1024,
                   C + (size_t)bm * 128 * 3072 + ccol, 1024, 3072);
}

// ---------------------------------------------------------------------------
// mLSTM elementwise scan over one T-chunk. z: [CH_M, 3072] = [q|k|v|i|f|o].
// One thread per (b, ch) channel; 4-deep load ring hides L2/L3 latency.
// State (c,n,m) persists in `st` ([3][8192]) across chunks (memset at t=0).
// ---------------------------------------------------------------------------
__global__ __launch_bounds__(64) void mlstm_scan(
    const float* __restrict__ z, const float* __restrict__ bg,
    float* __restrict__ hout, float* __restrict__ st, int nsteps)
{
  const int gt = blockIdx.x * 64 + threadIdx.x;   // 0..8191
  const int b = gt >> 9, hc = gt & 511;
  const float bi = bg[hc], bf = bg[512 + hc], bo = bg[1024 + hc];
  float c = st[gt], n = st[8192 + gt], m = st[16384 + gt];
  const float* zp = z + (size_t)b * 3072 + hc;
  float* hp = hout + (size_t)b * 512 + hc;
  float rq[4], rk[4], rv[4], ri[4], rf[4], ro[4];
#pragma unroll
  for (int d = 0; d < 4; ++d) {
    const float* p = zp + (size_t)d * BATCH * 3072;
    rq[d] = p[0];    rk[d] = p[512];  rv[d] = p[1024];
    ri[d] = p[1536]; rf[d] = p[2048]; ro[d] = p[2560];
  }
  for (int t = 0; t < nsteps; t += 4) {
#pragma unroll
    for (int u = 0; u < 4; ++u) {
      const int tt = t + u;
      float q = rq[u], k = rk[u] * SCALE_K, v = rv[u];
      float it = ri[u] + bi, ft = rf[u] + bf, ot = ro[u] + bo;
      if (tt + 4 < nsteps) {                       // refill ring slot u
        const float* p = zp + (size_t)(tt + 4) * BATCH * 3072;
        rq[u] = p[0];    rk[u] = p[512];  rv[u] = p[1024];
        ri[u] = p[1536]; rf[u] = p[2048]; ro[u] = p[2560];
      }
      float m2 = fmaxf(ft + m, it);
      float i  = expf(it - m2);
      float f  = expf(ft + m - m2);
      c = f * c + i * (v * k);
      n = f * n + i * k;
      m = m2;
      float hv = (1.f / (1.f + expf(-ot))) * (c * q) / fmaxf(fabsf(n * q), 1.f);
      hp[(size_t)tt * BATCH * 512] = hv;
    }
  }
  st[gt] = c; st[8192 + gt] = n; st[16384 + gt] = m;
}

// ---------------------------------------------------------------------------
// sLSTM, batch-parallel: one WG (512 threads, 8 waves) per batch row.
// The recurrence is independent per batch, so NO inter-WG sync at all.
// Per step: gates = R[2048,512] @ h[512]; 8 lanes cooperate per gate col
// (128 B contiguous R loads), h kept in 16 float4 regs per thread, 3x
// shfl_xor reduce, gate buffer + h in LDS, per-channel state in regs.
// State persists across chunk launches via hstate/sstate (memset at start).
// ---------------------------------------------------------------------------
__global__ __launch_bounds__(512, 1) void slstm_batch(
    const float* __restrict__ pre,   // [CH_M, 2048] x@W^T (no bias)
    const float* __restrict__ R,     // [2048, 512]
    const float* __restrict__ bias,  // [2048]
    float* __restrict__ hout,        // [CH_M, 512]
    float* __restrict__ hstate,      // [16][512] persist
    float* __restrict__ sstate,      // [3][16][512] persist (c,n,m)
    int nsteps)
{
  const int b   = blockIdx.x;        // batch 0..15
  const int tid = threadIdx.x;       // 0..511
  const int li  = tid & 7;           // lane-in-group (k slice)
  const int g   = tid >> 3;          // col group 0..63

  __shared__ float hl[512];
  __shared__ float gl[2048];

  const int c = tid;                 // this thread's state channel
  float st_c = sstate[b * 512 + c];
  float st_n = sstate[8192 + b * 512 + c];
  float st_m = sstate[16384 + b * 512 + c];
  const float bi = bias[c], bf = bias[512 + c];
  const float bz = bias[1024 + c], bo = bias[1536 + c];

  hl[c] = hstate[b * 512 + c];

  const float* Rg = R + (size_t)g * 512 + li * 4;   // col g, k-slice li
  __syncthreads();

  for (int t = 0; t < nsteps; ++t) {
    // prefetch this step's pre-activations (needed only after the passes)
    const float* prow = pre + (size_t)(t * BATCH + b) * 2048;
    float p_i = prow[c],        p_f = prow[512 + c];
    float p_z = prow[1024 + c], p_o = prow[1536 + c];

    // h -> registers (LDS broadcast, conflict-free)
    float4 hreg[16];
#pragma unroll
    for (int j = 0; j < 16; ++j)
      hreg[j] = *(const float4*)&hl[li * 4 + 32 * j];

    // 32 passes x 64 cols: dot(R[col,:], h)
    for (int p = 0; p < 32; ++p) {
      const float* Rp = Rg + (size_t)p * (64 * 512);
      float4 r0 = *(const float4*)(Rp + 0 * 32);
      float4 r1 = *(const float4*)(Rp + 1 * 32);
      float4 r2 = *(const float4*)(Rp + 2 * 32);
      float4 r3 = *(const float4*)(Rp + 3 * 32);
      float4 r4 = *(const float4*)(Rp + 4 * 32);
      float4 r5 = *(const float4*)(Rp + 5 * 32);
      float4 r6 = *(const float4*)(Rp + 6 * 32);
      float4 r7 = *(const float4*)(Rp + 7 * 32);
      float4 r8 = *(const float4*)(Rp + 8 * 32);
      float4 r9 = *(const float4*)(Rp + 9 * 32);
      float4 ra = *(const float4*)(Rp + 10 * 32);
      float4 rb = *(const float4*)(Rp + 11 * 32);
      float4 rc = *(const float4*)(Rp + 12 * 32);
      float4 rd = *(const float4*)(Rp + 13 * 32);
      float4 re = *(const float4*)(Rp + 14 * 32);
      float4 rf = *(const float4*)(Rp + 15 * 32);
      float acc = 0.f;
#define FMA4(rr, jj) \
      acc = fmaf(rr.x, hreg[jj].x, acc); acc = fmaf(rr.y, hreg[jj].y, acc); \
      acc = fmaf(rr.z, hreg[jj].z, acc); acc = fmaf(rr.w, hreg[jj].w, acc);
      FMA4(r0, 0)  FMA4(r1, 1)  FMA4(r2, 2)  FMA4(r3, 3)
      FMA4(r4, 4)  FMA4(r5, 5)  FMA4(r6, 6)  FMA4(r7, 7)
      FMA4(r8, 8)  FMA4(r9, 9)  FMA4(ra, 10) FMA4(rb, 11)
      FMA4(rc, 12) FMA4(rd, 13) FMA4(re, 14) FMA4(rf, 15)
#undef FMA4
      acc += __shfl_xor(acc, 1);
      acc += __shfl_xor(acc, 2);
      acc += __shfl_xor(acc, 4);
      if (li == 0) gl[p * 64 + g] = acc;
    }
    __syncthreads();   // gl complete; all hl reads done

    float it = gl[c]        + p_i + bi;
    float ft = gl[512 + c]  + p_f + bf;
    float zt = gl[1024 + c] + p_z + bz;
    float ot = gl[1536 + c] + p_o + bo;
    float m2 = fmaxf(ft + st_m, it);
    float i  = expf(it - m2);
    float f  = expf(ft + st_m - m2);
    st_c = f * st_c + i * tanhf(zt);
    st_n = f * st_n + i;
    st_m = m2;
    float hv = (1.f / (1.f + expf(-ot))) * st_c / st_n;
    hl[c] = hv;
    hout[(size_t)(t * BATCH + b) * 512 + c] = hv;
    __syncthreads();   // hl ready for next step
  }

  sstate[b * 512 + c] = st_c;
  sstate[8192 + b * 512 + c] = st_n;
  sstate[16384 + b * 512 + c] = st_m;
  hstate[b * 512 + c] = hl[c];
}

// ---------------------------------------------------------------------------
extern "C" void kernel_launch(void* const* d_in, const int* in_sizes, int n_in,
                              void* d_out, int out_size, void* d_ws, size_t ws_size,
                              hipStream_t stream) {
  const float* x    = (const float*)d_in[0];
  const float* Wup0 = (const float*)d_in[1];
  const float* Wq0  = (const float*)d_in[2];
  const float* Wk0  = (const float*)d_in[3];
  const float* Wv0  = (const float*)d_in[4];
  const float* Wg0  = (const float*)d_in[5];
  const float* bg0  = (const float*)d_in[6];
  const float* Ws1  = (const float*)d_in[7];
  const float* Rs1  = (const float*)d_in[8];
  const float* bs1  = (const float*)d_in[9];
  const float* Wup2 = (const float*)d_in[10];
  const float* Wq2  = (const float*)d_in[11];
  const float* Wk2  = (const float*)d_in[12];
  const float* Wv2  = (const float*)d_in[13];
  const float* Wg2  = (const float*)d_in[14];
  const float* bg2  = (const float*)d_in[15];
  const float* Ws3  = (const float*)d_in[16];
  const float* Rs3  = (const float*)d_in[17];
  const float* bs3  = (const float*)d_in[18];
  float* out = (float*)d_out;

  // ---- workspace layout (floats), ~84.5 MB total ----
  float* ws   = (float*)d_ws;
  float* up_c = ws;                        // CH_M*1024 =  4,194,304
  float* z_c  = up_c + 4194304;            // CH_M*3072 = 12,582,912 (pre aliases)
  float* h0_c = z_c + 12582912;            // CH_M*512  =  2,097,152 (also h2)
  float* h1_c = h0_c + 2097152;            // CH_M*512  =  2,097,152
  float* ctrl = h1_c + 2097152;            // persistent control region:
  float* mst0 = ctrl;                      //  3*8192 mLSTM-0 state
  float* mst2 = mst0 + 24576;              //  3*8192 mLSTM-2 state
  float* sst1 = mst2 + 24576;              //  3*8192 sLSTM-1 c,n,m
  float* sst3 = sst1 + 24576;              //  3*8192 sLSTM-3 c,n,m
  float* hst1 = sst3 + 24576;              //  8192   sLSTM-1 h
  float* hst3 = hst1 + 8192;               //  8192   sLSTM-3 h
  const size_t ctrl_bytes = (4 * 24576 + 2 * 8192) * sizeof(float);
  hipMemsetAsync(ctrl, 0, ctrl_bytes, stream);   // zero all persistent state

  dim3 blk(256);
  for (int c = 0; c < NCHUNK; ++c) {
    const size_t r0 = (size_t)c * CH_M;          // row offset of this chunk
    // ---- layer 0 (mLSTM) ----
    gemm_nt<true ><<<dim3( 8, 32), blk, 0, stream>>>(x + r0 * 512, Wup0, up_c, 512, 1024);
    gemm_qkvg     <<<dim3(24, 32), blk, 0, stream>>>(up_c, Wq0, Wk0, Wv0, Wg0, z_c);
    mlstm_scan    <<<128, 64, 0, stream>>>(z_c, bg0, h0_c, mst0, CH_T);
    // ---- layer 1 (sLSTM) ----
    gemm_nt<false><<<dim3(16, 32), blk, 0, stream>>>(h0_c, Ws1, z_c, 512, 2048);
    slstm_batch   <<<16, 512, 0, stream>>>(z_c, Rs1, bs1, h1_c, hst1, sst1, CH_T);
    // ---- layer 2 (mLSTM) ----
    gemm_nt<true ><<<dim3( 8, 32), blk, 0, stream>>>(h1_c, Wup2, up_c, 512, 1024);
    gemm_qkvg     <<<dim3(24, 32), blk, 0, stream>>>(up_c, Wq2, Wk2, Wv2, Wg2, z_c);
    mlstm_scan    <<<128, 64, 0, stream>>>(z_c, bg2, h0_c, mst2, CH_T);
    // ---- layer 3 (sLSTM) -> final output rows ----
    gemm_nt<false><<<dim3(16, 32), blk, 0, stream>>>(h0_c, Ws3, z_c, 512, 2048);
    slstm_batch   <<<16, 512, 0, stream>>>(z_c, Rs3, bs3, out + r0 * 512, hst3, sst3, CH_T);
  }
}

// Round 4
// 37539.444 us; speedup vs baseline: 3.8630x; 3.8630x over previous
//
#include <hip/hip_runtime.h>
#include <math.h>

#define T_SEQ 2048
#define BATCH 16
#define CH_T  256              // timesteps per chunk
#define CH_M  (CH_T*BATCH)     // 4096 rows per chunk
#define NCHUNK (T_SEQ/CH_T)    // 8
#define SCALE_K 0.125f         // 1/sqrt(H/NH) = 1/sqrt(64)
#define SPIN_LIMIT (1<<20)     // per-step poll budget (hang guard)

// ---------------------------------------------------------------------------
// Common tiled f32 GEMM body:  C[128,128] tile = act( A-tile @ W-tile^T ).
// ---------------------------------------------------------------------------
template<bool SILU>
__device__ __forceinline__ void gemm_body(const float* __restrict__ Ap,
                                          const float* __restrict__ Wp,
                                          float* __restrict__ Cp,
                                          int K, int ldc)
{
  __shared__ float As[16][132];
  __shared__ float Ws[16][132];
  const int tid = threadIdx.x;
  const int tx = tid & 15, ty = tid >> 4;
  float acc[8][8] = {};
  for (int k0 = 0; k0 < K; k0 += 16) {
#pragma unroll
    for (int i = 0; i < 2; ++i) {
      int idx = tid + i * 256;           // 0..511
      int r = idx >> 2, kq = idx & 3;    // row 0..127, k-quad 0..3
      float4 av = *(const float4*)(Ap + (size_t)r * K + k0 + kq * 4);
      float4 wv = *(const float4*)(Wp + (size_t)r * K + k0 + kq * 4);
      As[kq*4+0][r] = av.x; As[kq*4+1][r] = av.y;
      As[kq*4+2][r] = av.z; As[kq*4+3][r] = av.w;
      Ws[kq*4+0][r] = wv.x; Ws[kq*4+1][r] = wv.y;
      Ws[kq*4+2][r] = wv.z; Ws[kq*4+3][r] = wv.w;
    }
    __syncthreads();
#pragma unroll
    for (int kk = 0; kk < 16; ++kk) {
      float a[8], b[8];
      *(float4*)&a[0] = *(const float4*)&As[kk][ty*8];
      *(float4*)&a[4] = *(const float4*)&As[kk][ty*8+4];
      *(float4*)&b[0] = *(const float4*)&Ws[kk][tx*8];
      *(float4*)&b[4] = *(const float4*)&Ws[kk][tx*8+4];
#pragma unroll
      for (int i = 0; i < 8; ++i)
#pragma unroll
        for (int j = 0; j < 8; ++j)
          acc[i][j] = fmaf(a[i], b[j], acc[i][j]);
    }
    __syncthreads();
  }
#pragma unroll
  for (int i = 0; i < 8; ++i) {
    float* Cr = Cp + (size_t)(ty*8 + i) * ldc + tx*8;
#pragma unroll
    for (int j0 = 0; j0 < 8; j0 += 4) {
      float4 v;
      v.x = acc[i][j0+0]; v.y = acc[i][j0+1];
      v.z = acc[i][j0+2]; v.w = acc[i][j0+3];
      if (SILU) {
        v.x = v.x / (1.f + expf(-v.x));
        v.y = v.y / (1.f + expf(-v.y));
        v.z = v.z / (1.f + expf(-v.z));
        v.w = v.w / (1.f + expf(-v.w));
      }
      *(float4*)(Cr + j0) = v;
    }
  }
}

template<bool SILU>
__global__ __launch_bounds__(256, 2) void gemm_nt(
    const float* __restrict__ A, const float* __restrict__ W,
    float* __restrict__ C, int K, int ldc)
{
  const int bn = blockIdx.x, bm = blockIdx.y;
  gemm_body<SILU>(A + (size_t)bm * 128 * K,
                  W + (size_t)bn * 128 * K,
                  C + (size_t)bm * 128 * ldc + bn * 128, K, ldc);
}

// Fused q|k|v|gates GEMM -> C [M,3072] = [q|k|v|g]
__global__ __launch_bounds__(256, 2) void gemm_qkvg(
    const float* __restrict__ A,
    const float* __restrict__ Wq, const float* __restrict__ Wk,
    const float* __restrict__ Wv, const float* __restrict__ Wg,
    float* __restrict__ C)
{
  const int bn = blockIdx.x, bm = blockIdx.y;   // bn 0..23
  const float* W; int wrow, ccol;
  if (bn < 4)       { W = Wq; wrow = bn * 128;        ccol = bn * 128; }
  else if (bn < 8)  { W = Wk; wrow = (bn - 4) * 128;  ccol = 512  + (bn - 4) * 128; }
  else if (bn < 12) { W = Wv; wrow = (bn - 8) * 128;  ccol = 1024 + (bn - 8) * 128; }
  else              { W = Wg; wrow = (bn - 12) * 128; ccol = 1536 + (bn - 12) * 128; }
  gemm_body<false>(A + (size_t)bm * 128 * 1024,
                   W + (size_t)wrow * 1024,
                   C + (size_t)bm * 128 * 3072 + ccol, 1024, 3072);
}

// ---------------------------------------------------------------------------
// mLSTM elementwise scan over one T-chunk (unchanged; correct + cheap).
// ---------------------------------------------------------------------------
__global__ __launch_bounds__(64) void mlstm_scan(
    const float* __restrict__ z, const float* __restrict__ bg,
    float* __restrict__ hout, float* __restrict__ st, int nsteps)
{
  const int gt = blockIdx.x * 64 + threadIdx.x;   // 0..8191
  const int b = gt >> 9, hc = gt & 511;
  const float bi = bg[hc], bf = bg[512 + hc], bo = bg[1024 + hc];
  float c = st[gt], n = st[8192 + gt], m = st[16384 + gt];
  const float* zp = z + (size_t)b * 3072 + hc;
  float* hp = hout + (size_t)b * 512 + hc;
  float rq[4], rk[4], rv[4], ri[4], rf[4], ro[4];
#pragma unroll
  for (int d = 0; d < 4; ++d) {
    const float* p = zp + (size_t)d * BATCH * 3072;
    rq[d] = p[0];    rk[d] = p[512];  rv[d] = p[1024];
    ri[d] = p[1536]; rf[d] = p[2048]; ro[d] = p[2560];
  }
  for (int t = 0; t < nsteps; t += 4) {
#pragma unroll
    for (int u = 0; u < 4; ++u) {
      const int tt = t + u;
      float q = rq[u], k = rk[u] * SCALE_K, v = rv[u];
      float it = ri[u] + bi, ft = rf[u] + bf, ot = ro[u] + bo;
      if (tt + 4 < nsteps) {
        const float* p = zp + (size_t)(tt + 4) * BATCH * 3072;
        rq[u] = p[0];    rk[u] = p[512];  rv[u] = p[1024];
        ri[u] = p[1536]; rf[u] = p[2048]; ro[u] = p[2560];
      }
      float m2 = fmaxf(ft + m, it);
      float i  = expf(it - m2);
      float f  = expf(ft + m - m2);
      c = f * c + i * (v * k);
      n = f * n + i * k;
      m = m2;
      float hv = (1.f / (1.f + expf(-ot))) * (c * q) / fmaxf(fabsf(n * q), 1.f);
      hp[(size_t)tt * BATCH * 512] = hv;
    }
  }
  st[gt] = c; st[8192 + gt] = n; st[16384 + gt] = m;
}

// ---------------------------------------------------------------------------
// sLSTM v3: R held in REGISTERS, 16 WGs per batch, 16 batches concurrent.
//
// WG (b, j) (bid = b*16+j; same-j WGs share an R-slice AND land on the same
// XCD since 16 ≡ 0 mod 8) owns channels [32j, 32j+32) of batch b: 128 gate
// columns. 512 threads: thread (cc=tid>>3, li=tid&7) holds R rows for local
// cols {cc, cc+64}, k-slice [64li, 64li+64) => 2*16 float4 = 128 VGPRs.
// Per step: h[b] (2KB) -> LDS (agent loads), dot from regs, 3x shfl_xor,
// 32 state threads update c/n/m and store 32 h values (agent), 16-WG flag
// barrier per batch. R never touches memory after the initial stage.
// ---------------------------------------------------------------------------
__global__ __launch_bounds__(512, 2) void slstm_reg(
    const float* __restrict__ pre,   // [CH_M, 2048] x@W^T (no bias)
    const float* __restrict__ R,     // [2048, 512]
    const float* __restrict__ bias,  // [2048]
    float* __restrict__ hout,        // [CH_M, 512]
    float* __restrict__ hglob,       // [2][16][512] persist (zeroed)
    unsigned* __restrict__ flags,    // [16][16] persist (zeroed, monotone)
    float* __restrict__ sstate,      // [3][16][512] persist c,n,m (zeroed)
    int base, int nsteps)
{
  const int wg  = blockIdx.x;
  const int b   = wg >> 4;           // batch
  const int j   = wg & 15;           // channel-block
  const int tid = threadIdx.x;       // 0..511
  const int li  = tid & 7;           // k-slice
  const int cc  = tid >> 3;          // 0..63

  __shared__ float hl[8 * 68];       // h k-slices, padded stride 68
  __shared__ float gl[128];          // gate values (local cols)
  __shared__ float pl[128];          // staged pre values

  // ---- stage R slice into registers (once per launch) ----
  // local col lc: global R row = (lc>>5)*512 + j*32 + (lc&31)
  const float* Rr0 = R + (size_t)((cc >> 5) * 512 + j * 32 + (cc & 31)) * 512 + li * 64;
  const float* Rr1 = Rr0 + (size_t)2 * 512 * 512;   // lc+64 -> gate+2
  float4 Ra[16], Rb[16];
#pragma unroll
  for (int q = 0; q < 16; ++q) Ra[q] = *(const float4*)(Rr0 + q * 4);
#pragma unroll
  for (int q = 0; q < 16; ++q) Rb[q] = *(const float4*)(Rr1 + q * 4);

  // ---- per-channel state (32 state threads) ----
  const int s = tid;                  // valid when tid < 32
  const int ch = j * 32 + (tid & 31); // channel for state threads
  float st_c = 0.f, st_n = 0.f, st_m = 0.f, bi = 0.f, bf = 0.f, bz = 0.f, bo = 0.f;
  if (tid < 32) {
    const int si = b * 512 + ch;
    st_c = sstate[si]; st_n = sstate[8192 + si]; st_m = sstate[16384 + si];
    bi = bias[ch]; bf = bias[512 + ch]; bz = bias[1024 + ch]; bo = bias[1536 + ch];
  }

  for (int t = 0; t < nsteps; ++t) {
    const int ta = base + t;
    const float* hrd = hglob + (ta & 1) * 8192 + b * 512;
    float*       hwr = hglob + ((ta + 1) & 1) * 8192 + b * 512;

    // stage pre (128 vals) and h_prev (512 vals, device-coherent) into LDS
    if (tid < 128) {
      const int colg = (tid >> 5) * 512 + j * 32 + (tid & 31);
      pl[tid] = pre[(size_t)(t * BATCH + b) * 2048 + colg];
    }
    {
      float hv = __hip_atomic_load(hrd + tid, __ATOMIC_RELAXED,
                                   __HIP_MEMORY_SCOPE_AGENT);
      hl[(tid >> 6) * 68 + (tid & 63)] = hv;
    }
    __syncthreads();

    // dot(R[lc,:], h) from registers; h slice via broadcast LDS reads
    const float* hsl = &hl[li * 68];
    float acc0 = 0.f, acc1 = 0.f;
#pragma unroll
    for (int q = 0; q < 16; ++q) {
      float4 h4 = *(const float4*)(hsl + q * 4);
      float4 r0 = Ra[q], r1 = Rb[q];
      acc0 = fmaf(r0.x, h4.x, acc0); acc0 = fmaf(r0.y, h4.y, acc0);
      acc0 = fmaf(r0.z, h4.z, acc0); acc0 = fmaf(r0.w, h4.w, acc0);
      acc1 = fmaf(r1.x, h4.x, acc1); acc1 = fmaf(r1.y, h4.y, acc1);
      acc1 = fmaf(r1.z, h4.z, acc1); acc1 = fmaf(r1.w, h4.w, acc1);
    }
    acc0 += __shfl_xor(acc0, 1); acc0 += __shfl_xor(acc0, 2); acc0 += __shfl_xor(acc0, 4);
    acc1 += __shfl_xor(acc1, 1); acc1 += __shfl_xor(acc1, 2); acc1 += __shfl_xor(acc1, 4);
    if (li == 0) { gl[cc] = acc0; gl[cc + 64] = acc1; }
    __syncthreads();

    // state update: 32 threads, one channel each
    if (tid < 32) {
      float it = gl[s]      + pl[s]      + bi;
      float ft = gl[32 + s] + pl[32 + s] + bf;
      float zt = gl[64 + s] + pl[64 + s] + bz;
      float ot = gl[96 + s] + pl[96 + s] + bo;
      float m2 = fmaxf(ft + st_m, it);
      float i  = expf(it - m2);
      float f  = expf(ft + st_m - m2);
      st_c = f * st_c + i * tanhf(zt);
      st_n = f * st_n + i;
      st_m = m2;
      float hv = (1.f / (1.f + expf(-ot))) * st_c / st_n;
      __hip_atomic_store(hwr + ch, hv, __ATOMIC_RELAXED,
                         __HIP_MEMORY_SCOPE_AGENT);
      hout[(size_t)(t * BATCH + b) * 512 + ch] = hv;
    }
    __syncthreads();   // drains vmem (h stores) before flag release

    if (tid == 0)
      __hip_atomic_store(&flags[b * 16 + j], (unsigned)(ta + 1),
                         __ATOMIC_RELEASE, __HIP_MEMORY_SCOPE_AGENT);
    int my_to = 0;
    if (tid < 16) {
      int spins = 0;
      while (__hip_atomic_load(&flags[b * 16 + tid], __ATOMIC_ACQUIRE,
                               __HIP_MEMORY_SCOPE_AGENT) < (unsigned)(ta + 1)) {
        __builtin_amdgcn_s_sleep(1);
        if (++spins > SPIN_LIMIT) { my_to = 1; break; }
      }
    }
    if (__syncthreads_or(my_to)) break;   // uniform bail-out on timeout
  }

  if (tid < 32) {
    const int si = b * 512 + ch;
    sstate[si] = st_c; sstate[8192 + si] = st_n; sstate[16384 + si] = st_m;
  }
}

// ---------------------------------------------------------------------------
extern "C" void kernel_launch(void* const* d_in, const int* in_sizes, int n_in,
                              void* d_out, int out_size, void* d_ws, size_t ws_size,
                              hipStream_t stream) {
  const float* x    = (const float*)d_in[0];
  const float* Wup0 = (const float*)d_in[1];
  const float* Wq0  = (const float*)d_in[2];
  const float* Wk0  = (const float*)d_in[3];
  const float* Wv0  = (const float*)d_in[4];
  const float* Wg0  = (const float*)d_in[5];
  const float* bg0  = (const float*)d_in[6];
  const float* Ws1  = (const float*)d_in[7];
  const float* Rs1  = (const float*)d_in[8];
  const float* bs1  = (const float*)d_in[9];
  const float* Wup2 = (const float*)d_in[10];
  const float* Wq2  = (const float*)d_in[11];
  const float* Wk2  = (const float*)d_in[12];
  const float* Wv2  = (const float*)d_in[13];
  const float* Wg2  = (const float*)d_in[14];
  const float* bg2  = (const float*)d_in[15];
  const float* Ws3  = (const float*)d_in[16];
  const float* Rs3  = (const float*)d_in[17];
  const float* bs3  = (const float*)d_in[18];
  float* out = (float*)d_out;

  // ---- workspace layout (floats), ~85 MB total ----
  float* ws   = (float*)d_ws;
  float* up_c = ws;                        // CH_M*1024
  float* z_c  = up_c + 4194304;            // CH_M*3072 (pre aliases)
  float* h0_c = z_c + 12582912;            // CH_M*512
  float* h1_c = h0_c + 2097152;            // CH_M*512
  float* ctrl = h1_c + 2097152;            // persistent control region:
  float* mst0 = ctrl;                      //  3*8192 mLSTM-0 state
  float* mst2 = mst0 + 24576;              //  3*8192 mLSTM-2 state
  float* sst1 = mst2 + 24576;              //  3*8192 sLSTM-1 c,n,m
  float* sst3 = sst1 + 24576;              //  3*8192 sLSTM-3 c,n,m
  float* hg1  = sst3 + 24576;              //  2*8192 sLSTM-1 h dbuf
  float* hg3  = hg1 + 16384;               //  2*8192 sLSTM-3 h dbuf
  unsigned* fl1 = (unsigned*)(hg3 + 16384);//  256 flags
  unsigned* fl3 = fl1 + 256;               //  256 flags
  const size_t ctrl_bytes = (4 * 24576 + 2 * 16384) * sizeof(float)
                          + 2 * 256 * sizeof(unsigned);
  hipMemsetAsync(ctrl, 0, ctrl_bytes, stream);   // zero all persistent state

  dim3 blk(256);
  for (int c = 0; c < NCHUNK; ++c) {
    const size_t r0 = (size_t)c * CH_M;          // row offset of this chunk
    const int base = c * CH_T;                   // absolute step offset
    // ---- layer 0 (mLSTM) ----
    gemm_nt<true ><<<dim3( 8, 32), blk, 0, stream>>>(x + r0 * 512, Wup0, up_c, 512, 1024);
    gemm_qkvg     <<<dim3(24, 32), blk, 0, stream>>>(up_c, Wq0, Wk0, Wv0, Wg0, z_c);
    mlstm_scan    <<<128, 64, 0, stream>>>(z_c, bg0, h0_c, mst0, CH_T);
    // ---- layer 1 (sLSTM) ----
    gemm_nt<false><<<dim3(16, 32), blk, 0, stream>>>(h0_c, Ws1, z_c, 512, 2048);
    slstm_reg     <<<256, 512, 0, stream>>>(z_c, Rs1, bs1, h1_c, hg1, fl1, sst1, base, CH_T);
    // ---- layer 2 (mLSTM) ----
    gemm_nt<true ><<<dim3( 8, 32), blk, 0, stream>>>(h1_c, Wup2, up_c, 512, 1024);
    gemm_qkvg     <<<dim3(24, 32), blk, 0, stream>>>(up_c, Wq2, Wk2, Wv2, Wg2, z_c);
    mlstm_scan    <<<128, 64, 0, stream>>>(z_c, bg2, h0_c, mst2, CH_T);
    // ---- layer 3 (sLSTM) -> final output rows ----
    gemm_nt<false><<<dim3(16, 32), blk, 0, stream>>>(h0_c, Ws3, z_c, 512, 2048);
    slstm_reg     <<<256, 512, 0, stream>>>(z_c, Rs3, bs3, out + r0 * 512, hg3, fl3, sst3, base, CH_T);
  }
}